// Round 14
// baseline (1431.207 us; speedup 1.0000x reference)
//
#include <hip/hip_runtime.h>
#include <cstdint>
#include <cstddef>

#define NBLK 32
#define BLEN 128
#define WLEN 16
#define CEMB 16
#define NWRD 4096       // NBLK*BLEN
#define IDIM 1920
#define HID  256
#define G4   1024       // 4*HID
#define VOC  32000

typedef __attribute__((ext_vector_type(8))) short short8;
typedef __attribute__((ext_vector_type(4))) float f32x4;
typedef unsigned short u16;

static __device__ __forceinline__ float sigf(float x){ return 1.f/(1.f+__expf(-x)); }
static __device__ __forceinline__ u16 f2bf(float f){
  unsigned u = __float_as_uint(f);
  u = (u + 0x7fffu + ((u >> 16) & 1u)) >> 16;
  return (u16)u;
}
static __device__ __forceinline__ float bf2f(u16 b){
  return __uint_as_float(((unsigned)b) << 16);
}

// ---------------- K0a: pack conv weights -> Wt[1920][96] bf16 (one thread per element) ------
__global__ __launch_bounds__(256) void k_prep_conv(
    const float* __restrict__ cw0, const float* __restrict__ cb0,
    const float* __restrict__ cw1, const float* __restrict__ cb1,
    const float* __restrict__ cw2, const float* __restrict__ cb2,
    const float* __restrict__ cw3, const float* __restrict__ cb3,
    u16* __restrict__ Wt, float* __restrict__ ball)
{
  int idx = blockIdx.x*256 + threadIdx.x;   // over IDIM*96
  if (idx >= IDIM*96) return;
  int f = idx / 96, k = idx - f*96;
  int fl, fw, fn; const float* W; const float* B;
  if (f < 128)      { fl=f;     fw=2; fn=128;  W=cw0; B=cb0; }
  else if (f < 384) { fl=f-128; fw=3; fn=256;  W=cw1; B=cb1; }
  else if (f < 896) { fl=f-384; fw=4; fn=512;  W=cw2; B=cb2; }
  else              { fl=f-896; fw=5; fn=1024; W=cw3; B=cb3; }
  if (k == 0) ball[f] = B[fl];
  int kmax = fw*CEMB;
  Wt[idx] = (k < kmax) ? f2bf(W[(size_t)k*fn + fl]) : (u16)0;
}

// ---------------- K0b: all f32->bf16 weight conversions in ONE kernel ----------------
__global__ __launch_bounds__(256) void k_cvt_all(
    const float* __restrict__ hwnW, const float* __restrict__ hwgW,
    const float* __restrict__ lWih, const float* __restrict__ lWhh,
    const float* __restrict__ gWhh, const float* __restrict__ foW,
    u16* __restrict__ wnbf, u16* __restrict__ wgbf, u16* __restrict__ wihbf,
    u16* __restrict__ whhL, u16* __restrict__ whhG, u16* __restrict__ wbf)
{
  long idx = (long)blockIdx.x*256 + threadIdx.x;
  const long n1 = 3686400L;            // wnbf
  const long n2 = n1 + 3686400L;       // wgbf
  const long n3 = n2 + 1966080L;       // wihbf
  const long n4 = n3 + 262144L;        // whhL
  const long n5 = n4 + 262144L;        // whhG
  const long n6 = n5 + 8192000L;       // wbf
  if (idx < n1)      wnbf [idx]      = f2bf(hwnW[idx]);
  else if (idx < n2) wgbf [idx - n1] = f2bf(hwgW[idx - n1]);
  else if (idx < n3) wihbf[idx - n2] = f2bf(lWih[idx - n2]);
  else if (idx < n4) whhL [idx - n3] = f2bf(lWhh[idx - n3]);
  else if (idx < n5) whhG [idx - n4] = f2bf(gWhh[idx - n4]);
  else if (idx < n6) wbf  [idx - n5] = f2bf(foW [idx - n5]);
}

// ---------------- K1: char convs via MFMA -> ccbf only (bf16) ----------------
__global__ __launch_bounds__(256) void k_conv_mfma(
    const int* __restrict__ inp, const float* __restrict__ ctab,
    const u16* __restrict__ Wt, const float* __restrict__ ball,
    u16* __restrict__ ccbf)
{
  __shared__ __align__(16) u16 E[2][384];   // [word][24 rows x 16], rows 16..23 zero
  int tid = threadIdx.x;
  int n0 = blockIdx.x * 2;
  int wv = tid >> 6, l = tid & 63;
  int lr = l & 15, lk = l >> 4;

  for (int idx = tid; idx < 512; idx += 256) {
    int ws_ = idx >> 8, w = (idx >> 4) & 15, c = idx & 15;
    int ch = inp[(n0 + ws_)*WLEN + w];
    E[ws_][w*CEMB + c] = f2bf(ctab[ch*CEMB + c]);
  }
  for (int idx = tid; idx < 256; idx += 256) {
    int ws_ = idx >> 7;
    E[ws_][256 + (idx & 127)] = 0;
  }
  __syncthreads();

  short8 af[2][3];
#pragma unroll
  for (int ks = 0; ks < 3; ++ks) {
    int gk = ks*32 + lk*8;
    int w_ = gk >> 4, c0 = gk & 15;
    af[0][ks] = *(const short8*)&E[0][(lr + w_)*CEMB + c0];
    af[1][ks] = *(const short8*)&E[1][(lr + w_)*CEMB + c0];
  }

  for (int j = 0; j < 30; ++j) {
    int tile = wv*30 + j;
    int L = (tile < 8) ? 15 : (tile < 24 ? 14 : (tile < 56 ? 13 : 12));
    const u16* wp = Wt + (size_t)(tile*16 + lr)*96 + lk*8;
    short8 b0 = *(const short8*)(wp);
    short8 b1 = *(const short8*)(wp + 32);
    short8 b2 = *(const short8*)(wp + 64);
    f32x4 a0 = {}, a1 = {};
    a0 = __builtin_amdgcn_mfma_f32_16x16x32_bf16(af[0][0], b0, a0, 0, 0, 0);
    a1 = __builtin_amdgcn_mfma_f32_16x16x32_bf16(af[1][0], b0, a1, 0, 0, 0);
    a0 = __builtin_amdgcn_mfma_f32_16x16x32_bf16(af[0][1], b1, a0, 0, 0, 0);
    a1 = __builtin_amdgcn_mfma_f32_16x16x32_bf16(af[1][1], b1, a1, 0, 0, 0);
    a0 = __builtin_amdgcn_mfma_f32_16x16x32_bf16(af[0][2], b2, a0, 0, 0, 0);
    a1 = __builtin_amdgcn_mfma_f32_16x16x32_bf16(af[1][2], b2, a1, 0, 0, 0);
    float m0 = -1e30f, m1 = -1e30f;
#pragma unroll
    for (int r = 0; r < 4; ++r) {
      int i = lk*4 + r;
      if (i < L) { m0 = fmaxf(m0, a0[r]); m1 = fmaxf(m1, a1[r]); }
    }
    m0 = fmaxf(m0, __shfl_xor(m0, 16)); m0 = fmaxf(m0, __shfl_xor(m0, 32));
    m1 = fmaxf(m1, __shfl_xor(m1, 16)); m1 = fmaxf(m1, __shfl_xor(m1, 32));
    if (lk == 0) {
      int f = tile*16 + lr;
      float bv = ball[f];
      ccbf[(size_t)n0*IDIM + f]     = f2bf(tanhf(m0 + bv));
      ccbf[(size_t)(n0+1)*IDIM + f] = f2bf(tanhf(m1 + bv));
    }
  }
}

// ---------------- K2: highway via MFMA (dual-B) -> bf16 output; bf16 pass-through ----------
__global__ __launch_bounds__(256) void k_highway_mfma(
    const u16* __restrict__ Abf,   // ccbf [NWRD][IDIM]
    const u16* __restrict__ Wn, const float* __restrict__ bn,
    const u16* __restrict__ Wg, const float* __restrict__ bg,
    u16* __restrict__ outbf)       // hwbf [NWRD][IDIM]
{
  int tN = blockIdx.x * 64, tM = blockIdx.y * 64;
  int tid = threadIdx.x;
  int wave = tid >> 6, lane = tid & 63;
  int wm = (wave >> 1) * 32, wn = (wave & 1) * 32;
  int lhi = lane >> 4, llo = lane & 15;
  f32x4 aN[2][2] = {}, aG[2][2] = {};
  for (int k0 = 0; k0 < IDIM; k0 += 32) {
    int kof = k0 + lhi*8;
    short8 a0 = *(const short8*)(Abf + (size_t)(tM + wm + llo)*IDIM + kof);
    short8 a1 = *(const short8*)(Abf + (size_t)(tM + wm + 16 + llo)*IDIM + kof);
    short8 n0 = *(const short8*)(Wn + (size_t)(tN + wn + llo)*IDIM + kof);
    short8 n1 = *(const short8*)(Wn + (size_t)(tN + wn + 16 + llo)*IDIM + kof);
    short8 g0 = *(const short8*)(Wg + (size_t)(tN + wn + llo)*IDIM + kof);
    short8 g1 = *(const short8*)(Wg + (size_t)(tN + wn + 16 + llo)*IDIM + kof);
    aN[0][0] = __builtin_amdgcn_mfma_f32_16x16x32_bf16(a0, n0, aN[0][0], 0, 0, 0);
    aN[0][1] = __builtin_amdgcn_mfma_f32_16x16x32_bf16(a0, n1, aN[0][1], 0, 0, 0);
    aN[1][0] = __builtin_amdgcn_mfma_f32_16x16x32_bf16(a1, n0, aN[1][0], 0, 0, 0);
    aN[1][1] = __builtin_amdgcn_mfma_f32_16x16x32_bf16(a1, n1, aN[1][1], 0, 0, 0);
    aG[0][0] = __builtin_amdgcn_mfma_f32_16x16x32_bf16(a0, g0, aG[0][0], 0, 0, 0);
    aG[0][1] = __builtin_amdgcn_mfma_f32_16x16x32_bf16(a0, g1, aG[0][1], 0, 0, 0);
    aG[1][0] = __builtin_amdgcn_mfma_f32_16x16x32_bf16(a1, g0, aG[1][0], 0, 0, 0);
    aG[1][1] = __builtin_amdgcn_mfma_f32_16x16x32_bf16(a1, g1, aG[1][1], 0, 0, 0);
  }
#pragma unroll
  for (int mi = 0; mi < 2; ++mi)
#pragma unroll
    for (int ni = 0; ni < 2; ++ni) {
      int col = tN + wn + ni*16 + llo;
      float bnv = bn[col], bgv = bg[col];
#pragma unroll
      for (int r = 0; r < 4; ++r) {
        int row = tM + wm + mi*16 + lhi*4 + r;
        float nl = fmaxf(aN[mi][ni][r] + bnv, 0.f);
        float gt = sigf(aG[mi][ni][r] + bgv);
        float ccv = bf2f(Abf[(size_t)row*IDIM + col]);
        outbf[(size_t)row*IDIM + col] = f2bf(gt*nl + (1.f-gt)*ccv);
      }
    }
}

// ---------------- K2b: generic bf16 MFMA GEMM, f32 out, two biases ----------------
__global__ __launch_bounds__(256) void k_gemm_bf16(
    const u16* __restrict__ Abf, const u16* __restrict__ Bbf,
    const float* __restrict__ b1, const float* __restrict__ b2,
    float* __restrict__ C, int M, int N, int K)
{
  int tN = blockIdx.x * 64, tM = blockIdx.y * 64;
  int tid = threadIdx.x;
  int wave = tid >> 6, lane = tid & 63;
  int wm = (wave >> 1) * 32, wn = (wave & 1) * 32;
  int lhi = lane >> 4, llo = lane & 15;
  f32x4 acc[2][2] = {};
  for (int k0 = 0; k0 < K; k0 += 32) {
    int kof = k0 + lhi*8;
    short8 a0 = *(const short8*)(Abf + (size_t)(tM + wm + llo)*K + kof);
    short8 a1 = *(const short8*)(Abf + (size_t)(tM + wm + 16 + llo)*K + kof);
    short8 b0 = *(const short8*)(Bbf + (size_t)(tN + wn + llo)*K + kof);
    short8 b1v = *(const short8*)(Bbf + (size_t)(tN + wn + 16 + llo)*K + kof);
    acc[0][0] = __builtin_amdgcn_mfma_f32_16x16x32_bf16(a0, b0,  acc[0][0], 0, 0, 0);
    acc[0][1] = __builtin_amdgcn_mfma_f32_16x16x32_bf16(a0, b1v, acc[0][1], 0, 0, 0);
    acc[1][0] = __builtin_amdgcn_mfma_f32_16x16x32_bf16(a1, b0,  acc[1][0], 0, 0, 0);
    acc[1][1] = __builtin_amdgcn_mfma_f32_16x16x32_bf16(a1, b1v, acc[1][1], 0, 0, 0);
  }
#pragma unroll
  for (int mi = 0; mi < 2; ++mi)
#pragma unroll
    for (int ni = 0; ni < 2; ++ni) {
      int col = tN + wn + ni*16 + llo;
      float bv = b1[col] + (b2 ? b2[col] : 0.f);
#pragma unroll
      for (int r = 0; r < 4; ++r) {
        int row = tM + wm + mi*16 + lhi*4 + r;
        C[(size_t)row*N + col] = acc[mi][ni][r] + bv;
      }
    }
}

// ---------------- K3: generic f32 GEMM  C[M][N] = A[M][K] @ B[N][K]^T + b1 (+ b2) ----------------
__global__ __launch_bounds__(256) void k_gemm_f32(
    const float* __restrict__ A, const float* __restrict__ B,
    const float* __restrict__ b1, const float* __restrict__ b2,
    float* __restrict__ C, int M, int N, int K)
{
  __shared__ float As[16][68], Bs[16][68];
  int tM = blockIdx.x * 64, tN = blockIdx.y * 64;
  int tid = threadIdx.x, tx = tid & 15, ty = tid >> 4;
  float acc[4][4] = {};
  for (int k0 = 0; k0 < K; k0 += 16) {
    for (int i = tid; i < 1024; i += 256) {
      int m = i >> 4, k = i & 15;
      As[k][m] = A[(size_t)(tM+m)*K + k0 + k];
      Bs[k][m] = B[(size_t)(tN+m)*K + k0 + k];
    }
    __syncthreads();
#pragma unroll
    for (int kk = 0; kk < 16; ++kk) {
      float4 av = *(const float4*)&As[kk][ty*4];
      float4 bv = *(const float4*)&Bs[kk][tx*4];
      float a[4] = {av.x,av.y,av.z,av.w};
      float b[4] = {bv.x,bv.y,bv.z,bv.w};
#pragma unroll
      for (int i = 0; i < 4; ++i)
#pragma unroll
        for (int j = 0; j < 4; ++j) acc[i][j] += a[i]*b[j];
    }
    __syncthreads();
  }
  for (int i = 0; i < 4; ++i) {
    int row = tM + ty*4 + i;
    for (int j = 0; j < 4; ++j) {
      int col = tN + tx*4 + j;
      float v = acc[i][j] + b1[col] + (b2 ? b2[col] : 0.f);
      C[(size_t)row*N + col] = v;
    }
  }
}

// ---------------- K3b: fc GEMM, gather-A (outblks+out_glb concat), bf16 out to apre --------
__global__ __launch_bounds__(256) void k_fc_gemm(
    const float* __restrict__ ob, const float* __restrict__ og,
    const float* __restrict__ B, const float* __restrict__ bias,
    u16* __restrict__ apre)
{
  __shared__ float As[16][68], Bs[16][68];
  int tM = blockIdx.x * 64, tN = blockIdx.y * 64;
  int tid = threadIdx.x, tx = tid & 15, ty = tid >> 4;
  const int K = 512;
  float acc[4][4] = {};
  for (int k0 = 0; k0 < K; k0 += 16) {
    for (int i = tid; i < 1024; i += 256) {
      int m = i >> 4, k = i & 15;
      int r = tM + m, gk = k0 + k;
      As[k][m] = (gk < 256) ? ob[(size_t)(128 + r)*HID + gk]
                            : og[(size_t)(r >> 7)*HID + (gk - 256)];
      Bs[k][m] = B[(size_t)(tN+m)*K + gk];
    }
    __syncthreads();
#pragma unroll
    for (int kk = 0; kk < 16; ++kk) {
      float4 av = *(const float4*)&As[kk][ty*4];
      float4 bv = *(const float4*)&Bs[kk][tx*4];
      float a[4] = {av.x,av.y,av.z,av.w};
      float b[4] = {bv.x,bv.y,bv.z,bv.w};
#pragma unroll
      for (int i = 0; i < 4; ++i)
#pragma unroll
        for (int j = 0; j < 4; ++j) acc[i][j] += a[i]*b[j];
    }
    __syncthreads();
  }
  for (int i = 0; i < 4; ++i) {
    int row = tM + ty*4 + i;
    for (int j = 0; j < 4; ++j) {
      int col = tN + tx*4 + j;
      apre[(size_t)(128 + row)*HID + col] = f2bf(acc[i][j] + bias[col]);
    }
  }
}

// ---------------- K4: LSTM recurrence via MFMA + fused pair-pooling ----------
// R12 structure (floored at ~345us). Activation threads also emit max/avg pooling
// via one shfl_xor(h,1): even tid -> max at [n*256 + tid/2], odd tid -> mean at
// [n*256 + 128 + tid/2].  pooled==nullptr skips (global LSTM).
__global__ __launch_bounds__(512, 2) void k_lstm_rec(
    const float* __restrict__ xp,    // per block: [nsteps][1024]
    const u16* __restrict__ whhbf,   // [1024][256] bf16
    float* __restrict__ out,         // per block: [nsteps][256]
    float* __restrict__ pooled,      // per block: [nsteps][256] or nullptr
    int nsteps)
{
  __shared__ __align__(16) u16 WL[65536];   // 128 KB: rows 768..1023 swizzled
  __shared__ __align__(16) u16 hS[256];     // h in bf16
  __shared__ __align__(16) float gS[1024];  // h·Whh contributions
  int tid = threadIdx.x;
  int w = tid >> 6, l = tid & 63;
  int lr = l & 15, lk = l >> 4;

  for (int c = tid; c < 8192; c += 512) {
    int row = c >> 5, slot = c & 31;
    short8 v = *(const short8*)&whhbf[(size_t)(768 + row)*HID + slot*8];
    *(short8*)&WL[row*HID + ((slot ^ (row & 7)) << 3)] = v;
  }

  short8 af[6][8];
#pragma unroll
  for (int t2 = 0; t2 < 6; ++t2)
#pragma unroll
    for (int ks = 0; ks < 8; ++ks)
      af[t2][ks] = *(const short8*)&whhbf[(size_t)(w*96 + t2*16 + lr)*HID + ks*32 + lk*8];

  if (tid < 256) hS[tid] = 0;
  float c_st = 0.f;
  float hpend = 0.f, ppend = 0.f;
  __syncthreads();

  const float* xpb = xp + (size_t)blockIdx.x * nsteps * G4;
  float* outb = out + (size_t)blockIdx.x * nsteps * HID;
  float* poolb = pooled ? pooled + (size_t)blockIdx.x * nsteps * HID : nullptr;

  float xi = 0.f, xf = 0.f, xg = 0.f, xo = 0.f;
  if (tid < 256) {
    xi = xpb[tid]; xf = xpb[256+tid]; xg = xpb[512+tid]; xo = xpb[768+tid];
  }
  int pofs = (tid >> 1) + ((tid & 1) ? 128 : 0);   // pooled slot for this thread

  int r0 = 32*w + lr, r1 = r0 + 16;
  for (int t = 0; t < nsteps; ++t) {
    if (tid < 256 && t > 0) {
      outb[(size_t)(t-1)*HID + tid] = hpend;
      if (poolb) poolb[(size_t)(t-1)*HID + pofs] = ppend;
    }
    float nxi = 0.f, nxf = 0.f, nxg = 0.f, nxo = 0.f;
    if (tid < 256 && t + 1 < nsteps) {
      const float* xr = xpb + (size_t)(t+1)*G4;
      nxi = xr[tid]; nxf = xr[256+tid]; nxg = xr[512+tid]; nxo = xr[768+tid];
    }
    short8 bfk[8];
#pragma unroll
    for (int ks = 0; ks < 8; ++ks)
      bfk[ks] = *(const short8*)&hS[ks*32 + lk*8];

    f32x4 a[6] = {};
    f32x4 b0 = {}, b1 = {};
#pragma unroll
    for (int ks = 0; ks < 8; ++ks) {
#pragma unroll
      for (int t2 = 0; t2 < 6; ++t2)
        a[t2] = __builtin_amdgcn_mfma_f32_16x16x32_bf16(af[t2][ks], bfk[ks], a[t2], 0, 0, 0);
      int slot = ks*4 + lk;
      short8 w0 = *(const short8*)&WL[r0*HID + ((slot ^ (r0 & 7)) << 3)];
      short8 w1 = *(const short8*)&WL[r1*HID + ((slot ^ (r1 & 7)) << 3)];
      b0 = __builtin_amdgcn_mfma_f32_16x16x32_bf16(w0, bfk[ks], b0, 0, 0, 0);
      b1 = __builtin_amdgcn_mfma_f32_16x16x32_bf16(w1, bfk[ks], b1, 0, 0, 0);
    }
    if ((l & 15) == 0) {
#pragma unroll
      for (int t2 = 0; t2 < 6; ++t2)
        *(f32x4*)&gS[w*96 + t2*16 + lk*4] = a[t2];
      *(f32x4*)&gS[768 + w*32 + lk*4]      = b0;
      *(f32x4*)&gS[768 + w*32 + 16 + lk*4] = b1;
    }
    __syncthreads();
    if (tid < 256) {
      float iv = sigf(gS[tid] + xi);
      float fv = sigf(gS[256+tid] + xf);
      float gv = tanhf(gS[512+tid] + xg);
      float ov = sigf(gS[768+tid] + xo);
      c_st = fv*c_st + iv*gv;
      float h = ov*tanhf(c_st);
      hS[tid] = f2bf(h);
      hpend = h;
      float hp = __shfl_xor(h, 1);    // pair partner within wave
      ppend = (tid & 1) ? 0.5f*(h + hp) : fmaxf(h, hp);
      xi = nxi; xf = nxf; xg = nxg; xo = nxo;
    }
    __syncthreads();
  }
  if (tid < 256) {
    outb[(size_t)(nsteps-1)*HID + tid] = hpend;
    if (poolb) poolb[(size_t)(nsteps-1)*HID + pofs] = ppend;
  }
}

// ---------------- K6: fc1  blkrep[32][256] = pooled.reshape(32,32768) @ W^T + b ----------------
__global__ __launch_bounds__(256) void k_fc1(
    const float* __restrict__ pooled, const float* __restrict__ W,
    const float* __restrict__ bias, float* __restrict__ blkrep)
{
  __shared__ float buf[256];
  int b = blockIdx.x, cg = blockIdx.y, tid = threadIdx.x;
  const float* pb = pooled + (size_t)b*32768;
  float s[16] = {};
  for (int k = tid; k < 32768; k += 256) {
    float pv = pb[k];
#pragma unroll
    for (int cl = 0; cl < 16; ++cl)
      s[cl] += pv * W[(size_t)(cg*16 + cl)*32768 + k];
  }
  for (int cl = 0; cl < 16; ++cl) {
    buf[tid] = s[cl];
    __syncthreads();
    for (int off = 128; off; off >>= 1) {
      if (tid < off) buf[tid] += buf[tid + off];
      __syncthreads();
    }
    if (tid == 0) blkrep[b*HID + cg*16 + cl] = buf[0] + bias[cg*16 + cl];
    __syncthreads();
  }
}

// ---------------- K11: fc_out, 64x256 tiles, 1KB-contiguous wave stores ----------------
__global__ __launch_bounds__(256) void k_fcout(
    const u16* __restrict__ Abf,  // apre [4096][256]
    const u16* __restrict__ Wbf,  // foW  [32000][256]
    const float* __restrict__ bias,
    float* __restrict__ out)      // [4096][VOC]
{
  __shared__ __align__(16) float T[64][260];
  int tW = blockIdx.x * 64;    // word tile
  int tV = blockIdx.y * 256;   // vocab tile
  int tid = threadIdx.x;
  int wave = tid >> 6, lane = tid & 63;
  int lhi = lane >> 4, llo = lane & 15;
  int vbase = tV + wave*64;    // this wave's vocab quarter

  f32x4 acc[4][4] = {};   // [vocab-sub mt][word-sub nt]
  const int K = HID;
  for (int k0 = 0; k0 < K; k0 += 32) {
    int kof = k0 + lhi*8;
    short8 vfrag[4], wfrag[4];
#pragma unroll
    for (int mt = 0; mt < 4; ++mt)
      vfrag[mt] = *(const short8*)(Wbf + (size_t)(vbase + mt*16 + llo)*K + kof);
#pragma unroll
    for (int nt = 0; nt < 4; ++nt)
      wfrag[nt] = *(const short8*)(Abf + (size_t)(tW + nt*16 + llo)*K + kof);
#pragma unroll
    for (int mt = 0; mt < 4; ++mt)
#pragma unroll
      for (int nt = 0; nt < 4; ++nt)
        acc[mt][nt] = __builtin_amdgcn_mfma_f32_16x16x32_bf16(vfrag[mt], wfrag[nt], acc[mt][nt], 0, 0, 0);
  }
#pragma unroll
  for (int nt = 0; nt < 4; ++nt) {
    int wrow = nt*16 + llo;
#pragma unroll
    for (int mt = 0; mt < 4; ++mt)
      *(f32x4*)&T[wrow][wave*64 + mt*16 + lhi*4] = acc[mt][nt];
  }
  __syncthreads();
  f32x4 bv = *(const f32x4*)&bias[tV + lane*4];
#pragma unroll
  for (int i = 0; i < 16; ++i) {
    int wrow = wave*16 + i;
    f32x4 v = *(const f32x4*)&T[wrow][lane*4];
    v += bv;
    __builtin_nontemporal_store(v, (f32x4*)&out[(size_t)(tW + wrow)*VOC + tV + lane*4]);
  }
}

// ---------------- host ----------------
extern "C" void kernel_launch(void* const* d_in, const int* in_sizes, int n_in,
                              void* d_out, int out_size, void* d_ws, size_t ws_size,
                              hipStream_t stream) {
  (void)in_sizes; (void)n_in; (void)out_size; (void)ws_size;
  const int*   inp   = (const int*)d_in[0];
  const float* cemb  = (const float*)d_in[1];
  const float* cw0   = (const float*)d_in[2];
  const float* cb0   = (const float*)d_in[3];
  const float* cw1   = (const float*)d_in[4];
  const float* cb1   = (const float*)d_in[5];
  const float* cw2   = (const float*)d_in[6];
  const float* cb2   = (const float*)d_in[7];
  const float* cw3   = (const float*)d_in[8];
  const float* cb3   = (const float*)d_in[9];
  const float* hwnW  = (const float*)d_in[10];
  const float* hwnB  = (const float*)d_in[11];
  const float* hwgW  = (const float*)d_in[12];
  const float* hwgB  = (const float*)d_in[13];
  const float* lWih  = (const float*)d_in[14];
  const float* lWhh  = (const float*)d_in[15];
  const float* lbih  = (const float*)d_in[16];
  const float* lbhh  = (const float*)d_in[17];
  const float* fc1W  = (const float*)d_in[18];
  const float* fc1B  = (const float*)d_in[19];
  const float* gWih  = (const float*)d_in[20];
  const float* gWhh  = (const float*)d_in[21];
  const float* gbih  = (const float*)d_in[22];
  const float* gbhh  = (const float*)d_in[23];
  const float* fcW   = (const float*)d_in[24];
  const float* fcB   = (const float*)d_in[25];
  const float* foW   = (const float*)d_in[26];
  const float* foB   = (const float*)d_in[27];

  float* ws      = (float*)d_ws;
  float* xproj   = ws;                              // 4,194,304
  float* pooled  = xproj   + (size_t)NWRD*G4;       // 1,048,576
  float* blkrep  = pooled  + (size_t)NWRD*HID;      // 16,384 (padded to 64 rows)
  float* out_glb = blkrep  + 64*HID;                // 8,192
  float* A2      = out_glb + NBLK*HID;              // 2,031,616 (xpg = first 65,536)
  float* ball    = A2      + (size_t)3968*512;      // 1,920
  u16*   apre    = (u16*)(ball + 2048);             // 1,048,576 u16
  u16*   wbf     = apre    + (size_t)NWRD*HID;      // 8,192,000
  u16*   whhLbf  = wbf     + (size_t)VOC*HID;       // 262,144
  u16*   whhGbf  = whhLbf  + (size_t)G4*HID;        // 262,144
  u16*   wtall   = whhGbf  + (size_t)G4*HID;        // 184,320 (+pad)
  u16*   ccbf    = wtall   + 184320 + 64;           // 7,864,320
  u16*   hwbf    = ccbf    + (size_t)NWRD*IDIM;     // 7,864,320
  u16*   wnbf    = hwbf    + (size_t)NWRD*IDIM;     // 3,686,400
  u16*   wgbf    = wnbf    + (size_t)IDIM*IDIM;     // 3,686,400
  u16*   wihbf   = wgbf    + (size_t)IDIM*IDIM;     // 1,966,080

  float* outf    = (float*)d_out;
  float* outblks = outf + (size_t)NWRD*VOC;

  // 0. weight prep: conv pack + one merged cvt kernel + zero apre rows 0..127
  k_prep_conv<<<(IDIM*96)/256, 256, 0, stream>>>(cw0, cb0, cw1, cb1, cw2, cb2, cw3, cb3, wtall, ball);
  k_cvt_all<<<70528, 256, 0, stream>>>(hwnW, hwgW, lWih, lWhh, gWhh, foW,
                                       wnbf, wgbf, wihbf, whhLbf, whhGbf, wbf);
  hipMemsetAsync(apre, 0, (size_t)128*HID*sizeof(u16), stream);
  // 1. char conv features via MFMA (bf16 output only)
  k_conv_mfma<<<NWRD/2, 256, 0, stream>>>(inp, cemb, wtall, ball, ccbf);
  // 2. highway via MFMA -> hwbf (bf16, bf16 pass-through)
  k_highway_mfma<<<dim3(IDIM/64, NWRD/64), 256, 0, stream>>>(ccbf, wnbf, hwnB, wgbf, hwgB, hwbf);
  // 3. LSTM input projection via MFMA (+ both biases)
  k_gemm_bf16<<<dim3(G4/64, NWRD/64), 256, 0, stream>>>(hwbf, wihbf, lbih, lbhh, xproj, NWRD, G4, IDIM);
  // 4. local LSTM recurrence -> outblks + fused pooling
  k_lstm_rec<<<NBLK, 512, 0, stream>>>(xproj, whhLbf, outblks, pooled, BLEN);
  // 6. fc1 -> blkrep
  k_fc1<<<dim3(NBLK, 16), 256, 0, stream>>>(pooled, fc1W, fc1B, blkrep);
  // 7a. global LSTM input projection (rows padded to 64)
  k_gemm_f32<<<dim3(1, G4/64), 256, 0, stream>>>(blkrep, gWih, gbih, gbhh, A2, 64, G4, HID);
  // 7b. global recurrence (no pooling)
  k_lstm_rec<<<1, 512, 0, stream>>>(A2, whhGbf, out_glb, nullptr, NBLK);
  // 8+9+10 fused: fc GEMM with gather-A, bf16 epilogue direct to apre
  k_fc_gemm<<<dim3(3968/64, HID/64), 256, 0, stream>>>(outblks, out_glb, fcW, fcB, apre);
  // 11. fc_out MFMA (64x256 tiles, 1KB wave stores) -> outf
  k_fcout<<<dim3(NWRD/64, VOC/256), 256, 0, stream>>>(apre, wbf, foB, outf);
}

// Round 15
// 1366.255 us; speedup vs baseline: 1.0475x; 1.0475x over previous
//
#include <hip/hip_runtime.h>
#include <cstdint>
#include <cstddef>

#define NBLK 32
#define BLEN 128
#define WLEN 16
#define CEMB 16
#define NWRD 4096       // NBLK*BLEN
#define IDIM 1920
#define HID  256
#define G4   1024       // 4*HID
#define VOC  32000

typedef __attribute__((ext_vector_type(8))) short short8;
typedef __attribute__((ext_vector_type(4))) float f32x4;
typedef unsigned short u16;

static __device__ __forceinline__ float sigf(float x){ return 1.f/(1.f+__expf(-x)); }
static __device__ __forceinline__ u16 f2bf(float f){
  unsigned u = __float_as_uint(f);
  u = (u + 0x7fffu + ((u >> 16) & 1u)) >> 16;
  return (u16)u;
}
static __device__ __forceinline__ float bf2f(u16 b){
  return __uint_as_float(((unsigned)b) << 16);
}

// ---------------- K0a: pack conv weights -> Wt[1920][96] bf16 (one thread per element) ------
__global__ __launch_bounds__(256) void k_prep_conv(
    const float* __restrict__ cw0, const float* __restrict__ cb0,
    const float* __restrict__ cw1, const float* __restrict__ cb1,
    const float* __restrict__ cw2, const float* __restrict__ cb2,
    const float* __restrict__ cw3, const float* __restrict__ cb3,
    u16* __restrict__ Wt, float* __restrict__ ball)
{
  int idx = blockIdx.x*256 + threadIdx.x;   // over IDIM*96
  if (idx >= IDIM*96) return;
  int f = idx / 96, k = idx - f*96;
  int fl, fw, fn; const float* W; const float* B;
  if (f < 128)      { fl=f;     fw=2; fn=128;  W=cw0; B=cb0; }
  else if (f < 384) { fl=f-128; fw=3; fn=256;  W=cw1; B=cb1; }
  else if (f < 896) { fl=f-384; fw=4; fn=512;  W=cw2; B=cb2; }
  else              { fl=f-896; fw=5; fn=1024; W=cw3; B=cb3; }
  if (k == 0) ball[f] = B[fl];
  int kmax = fw*CEMB;
  Wt[idx] = (k < kmax) ? f2bf(W[(size_t)k*fn + fl]) : (u16)0;
}

// ---------------- K0b: all f32->bf16 weight conversions in ONE kernel ----------------
__global__ __launch_bounds__(256) void k_cvt_all(
    const float* __restrict__ hwnW, const float* __restrict__ hwgW,
    const float* __restrict__ lWih, const float* __restrict__ lWhh,
    const float* __restrict__ gWhh, const float* __restrict__ foW,
    u16* __restrict__ wnbf, u16* __restrict__ wgbf, u16* __restrict__ wihbf,
    u16* __restrict__ whhL, u16* __restrict__ whhG, u16* __restrict__ wbf)
{
  long idx = (long)blockIdx.x*256 + threadIdx.x;
  const long n1 = 3686400L;            // wnbf
  const long n2 = n1 + 3686400L;       // wgbf
  const long n3 = n2 + 1966080L;       // wihbf
  const long n4 = n3 + 262144L;        // whhL
  const long n5 = n4 + 262144L;        // whhG
  const long n6 = n5 + 8192000L;       // wbf
  if (idx < n1)      wnbf [idx]      = f2bf(hwnW[idx]);
  else if (idx < n2) wgbf [idx - n1] = f2bf(hwgW[idx - n1]);
  else if (idx < n3) wihbf[idx - n2] = f2bf(lWih[idx - n2]);
  else if (idx < n4) whhL [idx - n3] = f2bf(lWhh[idx - n3]);
  else if (idx < n5) whhG [idx - n4] = f2bf(gWhh[idx - n4]);
  else if (idx < n6) wbf  [idx - n5] = f2bf(foW [idx - n5]);
}

// ---------------- K1: char convs via MFMA -> ccbf only (bf16) ----------------
__global__ __launch_bounds__(256) void k_conv_mfma(
    const int* __restrict__ inp, const float* __restrict__ ctab,
    const u16* __restrict__ Wt, const float* __restrict__ ball,
    u16* __restrict__ ccbf)
{
  __shared__ __align__(16) u16 E[2][384];   // [word][24 rows x 16], rows 16..23 zero
  int tid = threadIdx.x;
  int n0 = blockIdx.x * 2;
  int wv = tid >> 6, l = tid & 63;
  int lr = l & 15, lk = l >> 4;

  for (int idx = tid; idx < 512; idx += 256) {
    int ws_ = idx >> 8, w = (idx >> 4) & 15, c = idx & 15;
    int ch = inp[(n0 + ws_)*WLEN + w];
    E[ws_][w*CEMB + c] = f2bf(ctab[ch*CEMB + c]);
  }
  for (int idx = tid; idx < 256; idx += 256) {
    int ws_ = idx >> 7;
    E[ws_][256 + (idx & 127)] = 0;
  }
  __syncthreads();

  short8 af[2][3];
#pragma unroll
  for (int ks = 0; ks < 3; ++ks) {
    int gk = ks*32 + lk*8;
    int w_ = gk >> 4, c0 = gk & 15;
    af[0][ks] = *(const short8*)&E[0][(lr + w_)*CEMB + c0];
    af[1][ks] = *(const short8*)&E[1][(lr + w_)*CEMB + c0];
  }

  for (int j = 0; j < 30; ++j) {
    int tile = wv*30 + j;
    int L = (tile < 8) ? 15 : (tile < 24 ? 14 : (tile < 56 ? 13 : 12));
    const u16* wp = Wt + (size_t)(tile*16 + lr)*96 + lk*8;
    short8 b0 = *(const short8*)(wp);
    short8 b1 = *(const short8*)(wp + 32);
    short8 b2 = *(const short8*)(wp + 64);
    f32x4 a0 = {}, a1 = {};
    a0 = __builtin_amdgcn_mfma_f32_16x16x32_bf16(af[0][0], b0, a0, 0, 0, 0);
    a1 = __builtin_amdgcn_mfma_f32_16x16x32_bf16(af[1][0], b0, a1, 0, 0, 0);
    a0 = __builtin_amdgcn_mfma_f32_16x16x32_bf16(af[0][1], b1, a0, 0, 0, 0);
    a1 = __builtin_amdgcn_mfma_f32_16x16x32_bf16(af[1][1], b1, a1, 0, 0, 0);
    a0 = __builtin_amdgcn_mfma_f32_16x16x32_bf16(af[0][2], b2, a0, 0, 0, 0);
    a1 = __builtin_amdgcn_mfma_f32_16x16x32_bf16(af[1][2], b2, a1, 0, 0, 0);
    float m0 = -1e30f, m1 = -1e30f;
#pragma unroll
    for (int r = 0; r < 4; ++r) {
      int i = lk*4 + r;
      if (i < L) { m0 = fmaxf(m0, a0[r]); m1 = fmaxf(m1, a1[r]); }
    }
    m0 = fmaxf(m0, __shfl_xor(m0, 16)); m0 = fmaxf(m0, __shfl_xor(m0, 32));
    m1 = fmaxf(m1, __shfl_xor(m1, 16)); m1 = fmaxf(m1, __shfl_xor(m1, 32));
    if (lk == 0) {
      int f = tile*16 + lr;
      float bv = ball[f];
      ccbf[(size_t)n0*IDIM + f]     = f2bf(tanhf(m0 + bv));
      ccbf[(size_t)(n0+1)*IDIM + f] = f2bf(tanhf(m1 + bv));
    }
  }
}

// ---------------- K2: highway via MFMA (dual-B) -> bf16 output; bf16 pass-through ----------
__global__ __launch_bounds__(256) void k_highway_mfma(
    const u16* __restrict__ Abf,   // ccbf [NWRD][IDIM]
    const u16* __restrict__ Wn, const float* __restrict__ bn,
    const u16* __restrict__ Wg, const float* __restrict__ bg,
    u16* __restrict__ outbf)       // hwbf [NWRD][IDIM]
{
  int tN = blockIdx.x * 64, tM = blockIdx.y * 64;
  int tid = threadIdx.x;
  int wave = tid >> 6, lane = tid & 63;
  int wm = (wave >> 1) * 32, wn = (wave & 1) * 32;
  int lhi = lane >> 4, llo = lane & 15;
  f32x4 aN[2][2] = {}, aG[2][2] = {};
  for (int k0 = 0; k0 < IDIM; k0 += 32) {
    int kof = k0 + lhi*8;
    short8 a0 = *(const short8*)(Abf + (size_t)(tM + wm + llo)*IDIM + kof);
    short8 a1 = *(const short8*)(Abf + (size_t)(tM + wm + 16 + llo)*IDIM + kof);
    short8 n0 = *(const short8*)(Wn + (size_t)(tN + wn + llo)*IDIM + kof);
    short8 n1 = *(const short8*)(Wn + (size_t)(tN + wn + 16 + llo)*IDIM + kof);
    short8 g0 = *(const short8*)(Wg + (size_t)(tN + wn + llo)*IDIM + kof);
    short8 g1 = *(const short8*)(Wg + (size_t)(tN + wn + 16 + llo)*IDIM + kof);
    aN[0][0] = __builtin_amdgcn_mfma_f32_16x16x32_bf16(a0, n0, aN[0][0], 0, 0, 0);
    aN[0][1] = __builtin_amdgcn_mfma_f32_16x16x32_bf16(a0, n1, aN[0][1], 0, 0, 0);
    aN[1][0] = __builtin_amdgcn_mfma_f32_16x16x32_bf16(a1, n0, aN[1][0], 0, 0, 0);
    aN[1][1] = __builtin_amdgcn_mfma_f32_16x16x32_bf16(a1, n1, aN[1][1], 0, 0, 0);
    aG[0][0] = __builtin_amdgcn_mfma_f32_16x16x32_bf16(a0, g0, aG[0][0], 0, 0, 0);
    aG[0][1] = __builtin_amdgcn_mfma_f32_16x16x32_bf16(a0, g1, aG[0][1], 0, 0, 0);
    aG[1][0] = __builtin_amdgcn_mfma_f32_16x16x32_bf16(a1, g0, aG[1][0], 0, 0, 0);
    aG[1][1] = __builtin_amdgcn_mfma_f32_16x16x32_bf16(a1, g1, aG[1][1], 0, 0, 0);
  }
#pragma unroll
  for (int mi = 0; mi < 2; ++mi)
#pragma unroll
    for (int ni = 0; ni < 2; ++ni) {
      int col = tN + wn + ni*16 + llo;
      float bnv = bn[col], bgv = bg[col];
#pragma unroll
      for (int r = 0; r < 4; ++r) {
        int row = tM + wm + mi*16 + lhi*4 + r;
        float nl = fmaxf(aN[mi][ni][r] + bnv, 0.f);
        float gt = sigf(aG[mi][ni][r] + bgv);
        float ccv = bf2f(Abf[(size_t)row*IDIM + col]);
        outbf[(size_t)row*IDIM + col] = f2bf(gt*nl + (1.f-gt)*ccv);
      }
    }
}

// ---------------- K2b: generic bf16 MFMA GEMM, f32 out, two biases ----------------
__global__ __launch_bounds__(256) void k_gemm_bf16(
    const u16* __restrict__ Abf, const u16* __restrict__ Bbf,
    const float* __restrict__ b1, const float* __restrict__ b2,
    float* __restrict__ C, int M, int N, int K)
{
  int tN = blockIdx.x * 64, tM = blockIdx.y * 64;
  int tid = threadIdx.x;
  int wave = tid >> 6, lane = tid & 63;
  int wm = (wave >> 1) * 32, wn = (wave & 1) * 32;
  int lhi = lane >> 4, llo = lane & 15;
  f32x4 acc[2][2] = {};
  for (int k0 = 0; k0 < K; k0 += 32) {
    int kof = k0 + lhi*8;
    short8 a0 = *(const short8*)(Abf + (size_t)(tM + wm + llo)*K + kof);
    short8 a1 = *(const short8*)(Abf + (size_t)(tM + wm + 16 + llo)*K + kof);
    short8 b0 = *(const short8*)(Bbf + (size_t)(tN + wn + llo)*K + kof);
    short8 b1v = *(const short8*)(Bbf + (size_t)(tN + wn + 16 + llo)*K + kof);
    acc[0][0] = __builtin_amdgcn_mfma_f32_16x16x32_bf16(a0, b0,  acc[0][0], 0, 0, 0);
    acc[0][1] = __builtin_amdgcn_mfma_f32_16x16x32_bf16(a0, b1v, acc[0][1], 0, 0, 0);
    acc[1][0] = __builtin_amdgcn_mfma_f32_16x16x32_bf16(a1, b0,  acc[1][0], 0, 0, 0);
    acc[1][1] = __builtin_amdgcn_mfma_f32_16x16x32_bf16(a1, b1v, acc[1][1], 0, 0, 0);
  }
#pragma unroll
  for (int mi = 0; mi < 2; ++mi)
#pragma unroll
    for (int ni = 0; ni < 2; ++ni) {
      int col = tN + wn + ni*16 + llo;
      float bv = b1[col] + (b2 ? b2[col] : 0.f);
#pragma unroll
      for (int r = 0; r < 4; ++r) {
        int row = tM + wm + mi*16 + lhi*4 + r;
        C[(size_t)row*N + col] = acc[mi][ni][r] + bv;
      }
    }
}

// ---------------- K3: generic f32 GEMM  C[M][N] = A[M][K] @ B[N][K]^T + b1 (+ b2) ----------------
__global__ __launch_bounds__(256) void k_gemm_f32(
    const float* __restrict__ A, const float* __restrict__ B,
    const float* __restrict__ b1, const float* __restrict__ b2,
    float* __restrict__ C, int M, int N, int K)
{
  __shared__ float As[16][68], Bs[16][68];
  int tM = blockIdx.x * 64, tN = blockIdx.y * 64;
  int tid = threadIdx.x, tx = tid & 15, ty = tid >> 4;
  float acc[4][4] = {};
  for (int k0 = 0; k0 < K; k0 += 16) {
    for (int i = tid; i < 1024; i += 256) {
      int m = i >> 4, k = i & 15;
      As[k][m] = A[(size_t)(tM+m)*K + k0 + k];
      Bs[k][m] = B[(size_t)(tN+m)*K + k0 + k];
    }
    __syncthreads();
#pragma unroll
    for (int kk = 0; kk < 16; ++kk) {
      float4 av = *(const float4*)&As[kk][ty*4];
      float4 bv = *(const float4*)&Bs[kk][tx*4];
      float a[4] = {av.x,av.y,av.z,av.w};
      float b[4] = {bv.x,bv.y,bv.z,bv.w};
#pragma unroll
      for (int i = 0; i < 4; ++i)
#pragma unroll
        for (int j = 0; j < 4; ++j) acc[i][j] += a[i]*b[j];
    }
    __syncthreads();
  }
  for (int i = 0; i < 4; ++i) {
    int row = tM + ty*4 + i;
    for (int j = 0; j < 4; ++j) {
      int col = tN + tx*4 + j;
      float v = acc[i][j] + b1[col] + (b2 ? b2[col] : 0.f);
      C[(size_t)row*N + col] = v;
    }
  }
}

// ---------------- K3b: fc GEMM, gather-A (outblks+out_glb concat), bf16 out to apre --------
__global__ __launch_bounds__(256) void k_fc_gemm(
    const float* __restrict__ ob, const float* __restrict__ og,
    const float* __restrict__ B, const float* __restrict__ bias,
    u16* __restrict__ apre)
{
  __shared__ float As[16][68], Bs[16][68];
  int tM = blockIdx.x * 64, tN = blockIdx.y * 64;
  int tid = threadIdx.x, tx = tid & 15, ty = tid >> 4;
  const int K = 512;
  float acc[4][4] = {};
  for (int k0 = 0; k0 < K; k0 += 16) {
    for (int i = tid; i < 1024; i += 256) {
      int m = i >> 4, k = i & 15;
      int r = tM + m, gk = k0 + k;
      As[k][m] = (gk < 256) ? ob[(size_t)(128 + r)*HID + gk]
                            : og[(size_t)(r >> 7)*HID + (gk - 256)];
      Bs[k][m] = B[(size_t)(tN+m)*K + gk];
    }
    __syncthreads();
#pragma unroll
    for (int kk = 0; kk < 16; ++kk) {
      float4 av = *(const float4*)&As[kk][ty*4];
      float4 bv = *(const float4*)&Bs[kk][tx*4];
      float a[4] = {av.x,av.y,av.z,av.w};
      float b[4] = {bv.x,bv.y,bv.z,bv.w};
#pragma unroll
      for (int i = 0; i < 4; ++i)
#pragma unroll
        for (int j = 0; j < 4; ++j) acc[i][j] += a[i]*b[j];
    }
    __syncthreads();
  }
  for (int i = 0; i < 4; ++i) {
    int row = tM + ty*4 + i;
    for (int j = 0; j < 4; ++j) {
      int col = tN + tx*4 + j;
      apre[(size_t)(128 + row)*HID + col] = f2bf(acc[i][j] + bias[col]);
    }
  }
}

// ---------------- K4: LSTM recurrence via MFMA (R13 version: proven 345us floor) ----------
__global__ __launch_bounds__(512, 2) void k_lstm_rec(
    const float* __restrict__ xp,    // per block: [nsteps][1024]
    const u16* __restrict__ whhbf,   // [1024][256] bf16
    float* __restrict__ out,         // per block: [nsteps][256]
    int nsteps)
{
  __shared__ __align__(16) u16 WL[65536];   // 128 KB: rows 768..1023 swizzled
  __shared__ __align__(16) u16 hS[256];     // h in bf16
  __shared__ __align__(16) float gS[1024];  // h·Whh contributions
  int tid = threadIdx.x;
  int w = tid >> 6, l = tid & 63;
  int lr = l & 15, lk = l >> 4;

  for (int c = tid; c < 8192; c += 512) {
    int row = c >> 5, slot = c & 31;
    short8 v = *(const short8*)&whhbf[(size_t)(768 + row)*HID + slot*8];
    *(short8*)&WL[row*HID + ((slot ^ (row & 7)) << 3)] = v;
  }

  short8 af[6][8];
#pragma unroll
  for (int t2 = 0; t2 < 6; ++t2)
#pragma unroll
    for (int ks = 0; ks < 8; ++ks)
      af[t2][ks] = *(const short8*)&whhbf[(size_t)(w*96 + t2*16 + lr)*HID + ks*32 + lk*8];

  if (tid < 256) hS[tid] = 0;
  float c_st = 0.f;
  float hpend = 0.f;
  __syncthreads();

  const float* xpb = xp + (size_t)blockIdx.x * nsteps * G4;
  float* outb = out + (size_t)blockIdx.x * nsteps * HID;

  float xi = 0.f, xf = 0.f, xg = 0.f, xo = 0.f;
  if (tid < 256) {
    xi = xpb[tid]; xf = xpb[256+tid]; xg = xpb[512+tid]; xo = xpb[768+tid];
  }

  int r0 = 32*w + lr, r1 = r0 + 16;
  for (int t = 0; t < nsteps; ++t) {
    if (tid < 256 && t > 0)
      outb[(size_t)(t-1)*HID + tid] = hpend;
    float nxi = 0.f, nxf = 0.f, nxg = 0.f, nxo = 0.f;
    if (tid < 256 && t + 1 < nsteps) {
      const float* xr = xpb + (size_t)(t+1)*G4;
      nxi = xr[tid]; nxf = xr[256+tid]; nxg = xr[512+tid]; nxo = xr[768+tid];
    }
    short8 bfk[8];
#pragma unroll
    for (int ks = 0; ks < 8; ++ks)
      bfk[ks] = *(const short8*)&hS[ks*32 + lk*8];

    f32x4 a[6] = {};
    f32x4 b0 = {}, b1 = {};
#pragma unroll
    for (int ks = 0; ks < 8; ++ks) {
#pragma unroll
      for (int t2 = 0; t2 < 6; ++t2)
        a[t2] = __builtin_amdgcn_mfma_f32_16x16x32_bf16(af[t2][ks], bfk[ks], a[t2], 0, 0, 0);
      int slot = ks*4 + lk;
      short8 w0 = *(const short8*)&WL[r0*HID + ((slot ^ (r0 & 7)) << 3)];
      short8 w1 = *(const short8*)&WL[r1*HID + ((slot ^ (r1 & 7)) << 3)];
      b0 = __builtin_amdgcn_mfma_f32_16x16x32_bf16(w0, bfk[ks], b0, 0, 0, 0);
      b1 = __builtin_amdgcn_mfma_f32_16x16x32_bf16(w1, bfk[ks], b1, 0, 0, 0);
    }
    if ((l & 15) == 0) {
#pragma unroll
      for (int t2 = 0; t2 < 6; ++t2)
        *(f32x4*)&gS[w*96 + t2*16 + lk*4] = a[t2];
      *(f32x4*)&gS[768 + w*32 + lk*4]      = b0;
      *(f32x4*)&gS[768 + w*32 + 16 + lk*4] = b1;
    }
    __syncthreads();
    if (tid < 256) {
      float iv = sigf(gS[tid] + xi);
      float fv = sigf(gS[256+tid] + xf);
      float gv = tanhf(gS[512+tid] + xg);
      float ov = sigf(gS[768+tid] + xo);
      c_st = fv*c_st + iv*gv;
      float h = ov*tanhf(c_st);
      hS[tid] = f2bf(h);
      hpend = h;
      xi = nxi; xf = nxf; xg = nxg; xo = nxo;
    }
    __syncthreads();
  }
  if (tid < 256)
    outb[(size_t)(nsteps-1)*HID + tid] = hpend;
}

// ---------------- K5: pair max/avg pooling ----------------
__global__ __launch_bounds__(256) void k_pool(const float* __restrict__ ob, float* __restrict__ pooled)
{
  int idx = blockIdx.x*256 + threadIdx.x;   // over NWRD*128
  int n = idx >> 7, p = idx & 127;
  float a = ob[(size_t)n*HID + 2*p];
  float b = ob[(size_t)n*HID + 2*p + 1];
  pooled[(size_t)n*HID + p]       = fmaxf(a, b);
  pooled[(size_t)n*HID + 128 + p] = 0.5f*(a + b);
}

// ---------------- K6: fc1  blkrep[32][256] = pooled.reshape(32,32768) @ W^T + b ----------------
__global__ __launch_bounds__(256) void k_fc1(
    const float* __restrict__ pooled, const float* __restrict__ W,
    const float* __restrict__ bias, float* __restrict__ blkrep)
{
  __shared__ float buf[256];
  int b = blockIdx.x, cg = blockIdx.y, tid = threadIdx.x;
  const float* pb = pooled + (size_t)b*32768;
  float s[16] = {};
  for (int k = tid; k < 32768; k += 256) {
    float pv = pb[k];
#pragma unroll
    for (int cl = 0; cl < 16; ++cl)
      s[cl] += pv * W[(size_t)(cg*16 + cl)*32768 + k];
  }
  for (int cl = 0; cl < 16; ++cl) {
    buf[tid] = s[cl];
    __syncthreads();
    for (int off = 128; off; off >>= 1) {
      if (tid < off) buf[tid] += buf[tid + off];
      __syncthreads();
    }
    if (tid == 0) blkrep[b*HID + cg*16 + cl] = buf[0] + bias[cg*16 + cl];
    __syncthreads();
  }
}

// ---------------- K11: fc_out, 64x256 tiles, 1KB-contiguous wave stores ----------------
__global__ __launch_bounds__(256) void k_fcout(
    const u16* __restrict__ Abf,  // apre [4096][256]
    const u16* __restrict__ Wbf,  // foW  [32000][256]
    const float* __restrict__ bias,
    float* __restrict__ out)      // [4096][VOC]
{
  __shared__ __align__(16) float T[64][260];
  int tW = blockIdx.x * 64;    // word tile
  int tV = blockIdx.y * 256;   // vocab tile
  int tid = threadIdx.x;
  int wave = tid >> 6, lane = tid & 63;
  int lhi = lane >> 4, llo = lane & 15;
  int vbase = tV + wave*64;    // this wave's vocab quarter

  f32x4 acc[4][4] = {};   // [vocab-sub mt][word-sub nt]
  const int K = HID;
  for (int k0 = 0; k0 < K; k0 += 32) {
    int kof = k0 + lhi*8;
    short8 vfrag[4], wfrag[4];
#pragma unroll
    for (int mt = 0; mt < 4; ++mt)
      vfrag[mt] = *(const short8*)(Wbf + (size_t)(vbase + mt*16 + llo)*K + kof);
#pragma unroll
    for (int nt = 0; nt < 4; ++nt)
      wfrag[nt] = *(const short8*)(Abf + (size_t)(tW + nt*16 + llo)*K + kof);
#pragma unroll
    for (int mt = 0; mt < 4; ++mt)
#pragma unroll
      for (int nt = 0; nt < 4; ++nt)
        acc[mt][nt] = __builtin_amdgcn_mfma_f32_16x16x32_bf16(vfrag[mt], wfrag[nt], acc[mt][nt], 0, 0, 0);
  }
#pragma unroll
  for (int nt = 0; nt < 4; ++nt) {
    int wrow = nt*16 + llo;
#pragma unroll
    for (int mt = 0; mt < 4; ++mt)
      *(f32x4*)&T[wrow][wave*64 + mt*16 + lhi*4] = acc[mt][nt];
  }
  __syncthreads();
  f32x4 bv = *(const f32x4*)&bias[tV + lane*4];
#pragma unroll
  for (int i = 0; i < 16; ++i) {
    int wrow = wave*16 + i;
    f32x4 v = *(const f32x4*)&T[wrow][lane*4];
    v += bv;
    __builtin_nontemporal_store(v, (f32x4*)&out[(size_t)(tW + wrow)*VOC + tV + lane*4]);
  }
}

// ---------------- host ----------------
extern "C" void kernel_launch(void* const* d_in, const int* in_sizes, int n_in,
                              void* d_out, int out_size, void* d_ws, size_t ws_size,
                              hipStream_t stream) {
  (void)in_sizes; (void)n_in; (void)out_size; (void)ws_size;
  const int*   inp   = (const int*)d_in[0];
  const float* cemb  = (const float*)d_in[1];
  const float* cw0   = (const float*)d_in[2];
  const float* cb0   = (const float*)d_in[3];
  const float* cw1   = (const float*)d_in[4];
  const float* cb1   = (const float*)d_in[5];
  const float* cw2   = (const float*)d_in[6];
  const float* cb2   = (const float*)d_in[7];
  const float* cw3   = (const float*)d_in[8];
  const float* cb3   = (const float*)d_in[9];
  const float* hwnW  = (const float*)d_in[10];
  const float* hwnB  = (const float*)d_in[11];
  const float* hwgW  = (const float*)d_in[12];
  const float* hwgB  = (const float*)d_in[13];
  const float* lWih  = (const float*)d_in[14];
  const float* lWhh  = (const float*)d_in[15];
  const float* lbih  = (const float*)d_in[16];
  const float* lbhh  = (const float*)d_in[17];
  const float* fc1W  = (const float*)d_in[18];
  const float* fc1B  = (const float*)d_in[19];
  const float* gWih  = (const float*)d_in[20];
  const float* gWhh  = (const float*)d_in[21];
  const float* gbih  = (const float*)d_in[22];
  const float* gbhh  = (const float*)d_in[23];
  const float* fcW   = (const float*)d_in[24];
  const float* fcB   = (const float*)d_in[25];
  const float* foW   = (const float*)d_in[26];
  const float* foB   = (const float*)d_in[27];

  float* ws      = (float*)d_ws;
  float* xproj   = ws;                              // 4,194,304
  float* pooled  = xproj   + (size_t)NWRD*G4;       // 1,048,576
  float* blkrep  = pooled  + (size_t)NWRD*HID;      // 16,384 (padded to 64 rows)
  float* out_glb = blkrep  + 64*HID;                // 8,192
  float* A2      = out_glb + NBLK*HID;              // 2,031,616 (xpg = first 65,536)
  float* ball    = A2      + (size_t)3968*512;      // 1,920
  u16*   apre    = (u16*)(ball + 2048);             // 1,048,576 u16
  u16*   wbf     = apre    + (size_t)NWRD*HID;      // 8,192,000
  u16*   whhLbf  = wbf     + (size_t)VOC*HID;       // 262,144
  u16*   whhGbf  = whhLbf  + (size_t)G4*HID;        // 262,144
  u16*   wtall   = whhGbf  + (size_t)G4*HID;        // 184,320 (+pad)
  u16*   ccbf    = wtall   + 184320 + 64;           // 7,864,320
  u16*   hwbf    = ccbf    + (size_t)NWRD*IDIM;     // 7,864,320
  u16*   wnbf    = hwbf    + (size_t)NWRD*IDIM;     // 3,686,400
  u16*   wgbf    = wnbf    + (size_t)IDIM*IDIM;     // 3,686,400
  u16*   wihbf   = wgbf    + (size_t)IDIM*IDIM;     // 1,966,080

  float* outf    = (float*)d_out;
  float* outblks = outf + (size_t)NWRD*VOC;

  // 0. weight prep: conv pack + one merged cvt kernel + zero apre rows 0..127
  k_prep_conv<<<(IDIM*96)/256, 256, 0, stream>>>(cw0, cb0, cw1, cb1, cw2, cb2, cw3, cb3, wtall, ball);
  k_cvt_all<<<70528, 256, 0, stream>>>(hwnW, hwgW, lWih, lWhh, gWhh, foW,
                                       wnbf, wgbf, wihbf, whhLbf, whhGbf, wbf);
  hipMemsetAsync(apre, 0, (size_t)128*HID*sizeof(u16), stream);
  // 1. char conv features via MFMA (bf16 output only)
  k_conv_mfma<<<NWRD/2, 256, 0, stream>>>(inp, cemb, wtall, ball, ccbf);
  // 2. highway via MFMA -> hwbf (bf16, bf16 pass-through)
  k_highway_mfma<<<dim3(IDIM/64, NWRD/64), 256, 0, stream>>>(ccbf, wnbf, hwnB, wgbf, hwgB, hwbf);
  // 3. LSTM input projection via MFMA (+ both biases)
  k_gemm_bf16<<<dim3(G4/64, NWRD/64), 256, 0, stream>>>(hwbf, wihbf, lbih, lbhh, xproj, NWRD, G4, IDIM);
  // 4. local LSTM recurrence -> outblks (R13 version)
  k_lstm_rec<<<NBLK, 512, 0, stream>>>(xproj, whhLbf, outblks, BLEN);
  // 5. pooling (separate kernel — fusing into recurrence cost +53us, R14 lesson)
  k_pool<<<(NWRD*128)/256, 256, 0, stream>>>(outblks, pooled);
  // 6. fc1 -> blkrep
  k_fc1<<<dim3(NBLK, 16), 256, 0, stream>>>(pooled, fc1W, fc1B, blkrep);
  // 7a. global LSTM input projection (rows padded to 64)
  k_gemm_f32<<<dim3(1, G4/64), 256, 0, stream>>>(blkrep, gWih, gbih, gbhh, A2, 64, G4, HID);
  // 7b. global recurrence
  k_lstm_rec<<<1, 512, 0, stream>>>(A2, whhGbf, out_glb, NBLK);
  // 8+9+10 fused: fc GEMM with gather-A, bf16 epilogue direct to apre
  k_fc_gemm<<<dim3(3968/64, HID/64), 256, 0, stream>>>(outblks, out_glb, fcW, fcB, apre);
  // 11. fc_out MFMA (64x256 tiles, 1KB wave stores) -> outf
  k_fcout<<<dim3(NWRD/64, VOC/256), 256, 0, stream>>>(apre, wbf, foB, outf);
}